// Round 2
// baseline (757.046 us; speedup 1.0000x reference)
//
#include <hip/hip_runtime.h>

#define NB 16
#define NC 256
#define NH 64
#define NW 64
#define NK 1024
#define HW (NH * NW)          // 4096
#define NPOS (NB * HW)        // 65536
#define NOUT (NB * NC * HW)   // 16777216
#define NSLOT 256             // loss accumulator slots (atomic spreading)

__device__ __forceinline__ float sq_rn(float x) { return __fmul_rn(x, x); }

// Exact replica of numpy pairwise_sum for sum(a*a) over n=256 (verified R2/R4).
__device__ __forceinline__ float pairwise_sumsq_256(const float* __restrict__ a,
                                                    int stride) {
    float s_half[2];
#pragma unroll
    for (int h = 0; h < 2; ++h) {
        const float* base = a + (size_t)(h * 128) * stride;
        float r[8];
#pragma unroll
        for (int j = 0; j < 8; ++j) r[j] = sq_rn(base[(size_t)j * stride]);
        for (int i = 8; i < 128; i += 8) {
#pragma unroll
            for (int j = 0; j < 8; ++j)
                r[j] = __fadd_rn(r[j], sq_rn(base[(size_t)(i + j) * stride]));
        }
        s_half[h] = __fadd_rn(
            __fadd_rn(__fadd_rn(r[0], r[1]), __fadd_rn(r[2], r[3])),
            __fadd_rn(__fadd_rn(r[4], r[5]), __fadd_rn(r[6], r[7])));
    }
    return __fadd_rn(s_half[0], s_half[1]);
}

// ---------------------------------------------------------------------------
// Kernel A: cnorm[k] = numpy-fp32 sum(codebook[k]^2)
// ---------------------------------------------------------------------------
__global__ __launch_bounds__(256) void cnorm_kernel(const float* __restrict__ cb,
                                                    float* __restrict__ cnorm) {
    int k = blockIdx.x * 256 + threadIdx.x;
    if (k < NK) {
        cnorm[k] = pairwise_sumsq_256(cb + (size_t)k * NC, 1);
    }
}

// ---------------------------------------------------------------------------
// Kernel A2: cbT[d][k] = cb[k][d]  (d-major codebook for streamed argmin loads)
// ---------------------------------------------------------------------------
__global__ __launch_bounds__(256) void transpose_cb_kernel(const float* __restrict__ cb,
                                                           float* __restrict__ cbT) {
    const int k = blockIdx.x;    // 0..1023
    const int d = threadIdx.x;   // 0..255
    cbT[(size_t)d * NK + k] = cb[(size_t)k * NC + d];
}

// ---------------------------------------------------------------------------
// Kernel B (R8): occupancy fix. R7 post-mortem: VALUBusy 72% but FMA issue
// only 46% of cycles — stalls exposed because 68KB LDS @ 256-thr blocks gave
// 2 blocks/CU = 2 waves/SIMD. R8: 512-thr blocks (8 waves) share the same
// 64KB z_lds, 1024 codes in 2 passes -> 2 blocks/CU = 16 waves/CU = 4
// waves/SIMD (2x latency hiding). Register-lean 4-dim chunks (no hand
// ping-pong — R7 showed the compiler collapses it); __launch_bounds__(512,4)
// caps VGPR at 128 so occupancy holds.
// Bit-exact vs R6/R7: acc = same sequential __fmaf_rn chain over ascending d;
// score = fl(fl(znorm+cnorm) - 2*dot); per-thread k strictly ascending across
// passes (pass stride 64 >= max cg*8+7); tie-breaks kept in both reduces.
// ---------------------------------------------------------------------------
__global__ __launch_bounds__(512, 4) void argmin_kernel(const float* __restrict__ z,
                                                        const float* __restrict__ cbT,
                                                        const float* __restrict__ cnorm,
                                                        int* __restrict__ idx_ws,
                                                        float* __restrict__ idx_out) {
    __shared__ float z_lds[256][64];      // 65536 B, [d][p]
    __shared__ float znorm_s[64];         //   256 B
    __shared__ float red_v[8][64];        //  2048 B
    __shared__ int   red_i[8][64];        //  2048 B   -> ~68.25 KB, 2 blk/CU

    const int blk = blockIdx.x;           // 0..1023
    const int b = blk >> 6;               // batch
    const int hw0 = (blk & 63) * 64;      // h-row base (64 contiguous positions)
    const int t = threadIdx.x;            // 0..511
    const int lane = t & 63;
    const int wave = t >> 6;              // 0..7
    const int pg = lane & 7;              // position group (8 pos each)
    const int cg = lane >> 3;             // code group (8 codes each)

    const float* zg = z + (size_t)b * (NC * HW) + hw0;

    // ---- stage z d-major: 8 iters of float4 across 512 threads (coalesced)
#pragma unroll
    for (int i = 0; i < 8; ++i) {
        const int flat4 = i * 2048 + t * 4;   // multiple of 4
        const int d = flat4 >> 6;
        const int p = flat4 & 63;
        const float4 v = *(const float4*)(zg + (size_t)d * HW + p);
        *(float4*)&z_lds[d][p] = v;
    }
    // numpy-exact znorm (same global-strided code path verified in R2/R4)
    if (wave == 0) znorm_s[lane] = pairwise_sumsq_256(zg + lane, HW);
    __syncthreads();                      // the ONLY pre-reduce barrier

    float best[8];
    int bid[8];
#pragma unroll
    for (int i = 0; i < 8; ++i) { best[i] = 3.4e38f; bid[i] = 0; }

#pragma unroll 1
    for (int pass = 0; pass < 2; ++pass) {
        float acc[8][8];
#pragma unroll
        for (int i = 0; i < 8; ++i)
#pragma unroll
            for (int j = 0; j < 8; ++j) acc[i][j] = 0.f;

        // wave owns codes [wave*128, wave*128+128); this pass's 64 of them.
        const int k0 = wave * 128 + pass * 64 + cg * 8;
        const float* cp = cbT + k0;       // column base; row stride NK floats

#pragma unroll 1
        for (int it = 0; it < 64; ++it) { // 4 dims per chunk, register-lean
            const int ds = it * 4;
            float4 cbuf[8];               // 32 VGPR in flight
#pragma unroll
            for (int q = 0; q < 8; ++q)
                cbuf[q] = *(const float4*)(cp + (size_t)(ds + (q >> 1)) * NK
                                              + (q & 1) * 4);
#pragma unroll
            for (int dl = 0; dl < 4; ++dl) {
                const int d = ds + dl;
                const float4 za = *(const float4*)&z_lds[d][pg * 8];
                const float4 zb = *(const float4*)&z_lds[d][pg * 8 + 4];
                const float zf[8] = {za.x, za.y, za.z, za.w,
                                     zb.x, zb.y, zb.z, zb.w};
                const float4 ca = cbuf[dl * 2];
                const float4 cc = cbuf[dl * 2 + 1];
                const float cf[8] = {ca.x, ca.y, ca.z, ca.w,
                                     cc.x, cc.y, cc.z, cc.w};
#pragma unroll
                for (int i = 0; i < 8; ++i)
#pragma unroll
                    for (int j = 0; j < 8; ++j)
                        acc[i][j] = __fmaf_rn(zf[i], cf[j], acc[i][j]);
            }
        }

        // scores for this pass's 8 codes of this thread (k ascending within
        // thread across passes -> strict < keeps first occurrence)
        const float4 cn0 = *(const float4*)(cnorm + k0);
        const float4 cn1 = *(const float4*)(cnorm + k0 + 4);
        const float cnf[8] = {cn0.x, cn0.y, cn0.z, cn0.w,
                              cn1.x, cn1.y, cn1.z, cn1.w};
        float znl[8];                     // re-read per pass: keeps them cold
#pragma unroll
        for (int i = 0; i < 8; ++i) znl[i] = znorm_s[pg * 8 + i];
#pragma unroll
        for (int j = 0; j < 8; ++j) {
            const int k = k0 + j;
#pragma unroll
            for (int i = 0; i < 8; ++i) {
                const float sc = __fsub_rn(__fadd_rn(znl[i], cnf[j]),
                                           __fmul_rn(2.0f, acc[i][j]));
                if (sc < best[i]) { best[i] = sc; bid[i] = k; }
            }
        }
    }

    // ---- reduce across cg (lane stride 8). k-ranges of different cg lanes
    //      INTERLEAVE across passes -> must tie-break on lower index to match
    //      np.argmin first-occurrence (R5 bug).
#pragma unroll
    for (int off = 32; off >= 8; off >>= 1) {
#pragma unroll
        for (int i = 0; i < 8; ++i) {
            const float v = __shfl_down(best[i], off, 64);
            const int d2 = __shfl_down(bid[i], off, 64);
            if (v < best[i] || (v == best[i] && d2 < bid[i])) {
                best[i] = v;
                bid[i] = d2;
            }
        }
    }
    if (cg == 0) {
#pragma unroll
        for (int i = 0; i < 8; ++i) {
            red_v[wave][pg * 8 + i] = best[i];
            red_i[wave][pg * 8 + i] = bid[i];
        }
    }
    __syncthreads();

    // ---- final reduce across 8 waves (disjoint ascending k ranges; index
    //      tie-break kept anyway for safety)
    if (t < 64) {
        float bv = red_v[0][t];
        int bi = red_i[0][t];
#pragma unroll
        for (int w = 1; w < 8; ++w) {
            const float v = red_v[w][t];
            const int i2 = red_i[w][t];
            if (v < bv || (v == bv && i2 < bi)) { bv = v; bi = i2; }
        }
        const int g = b * HW + hw0 + t;
        idx_ws[g] = bi;
        idx_out[g] = (float)bi;
    }
}

// ---------------------------------------------------------------------------
// Kernel C: out[b,c,h,w] = cb[idx[b,h,w]][c]; accumulate sum((zq - z)^2)
// Atomics spread over NSLOT slots (R7 win).
// ---------------------------------------------------------------------------
__global__ __launch_bounds__(256) void gather_loss_kernel(const float* __restrict__ z,
                                                          const float* __restrict__ cb,
                                                          const int* __restrict__ idx_ws,
                                                          float* __restrict__ out,
                                                          double* __restrict__ loss_acc) {
    const unsigned g = blockIdx.x * 256u + threadIdx.x;  // float4 index
    const unsigned e = g * 4u;                           // element index
    const unsigned w = e & 63u;
    const unsigned h = (e >> 6) & 63u;
    const unsigned c = (e >> 12) & 255u;
    const unsigned b = e >> 20;

    const unsigned p = b * HW + h * NW + w;  // divisible by 4

    const int4 iv = *(const int4*)(idx_ws + p);
    const float4 z4 = *(const float4*)(z + e);

    float4 o;
    o.x = cb[(size_t)iv.x * NC + c];
    o.y = cb[(size_t)iv.y * NC + c];
    o.z = cb[(size_t)iv.z * NC + c];
    o.w = cb[(size_t)iv.w * NC + c];

    *(float4*)(out + e) = o;

    const float d0 = o.x - z4.x;
    const float d1 = o.y - z4.y;
    const float d2 = o.z - z4.z;
    const float d3 = o.w - z4.w;
    float part = d0 * d0 + d1 * d1 + d2 * d2 + d3 * d3;

#pragma unroll
    for (int off = 32; off > 0; off >>= 1) part += __shfl_down(part, off, 64);

    __shared__ float wsum[4];
    const int lane = threadIdx.x & 63;
    const int wave = threadIdx.x >> 6;
    if (lane == 0) wsum[wave] = part;
    __syncthreads();
    if (threadIdx.x == 0) {
        float s = wsum[0] + wsum[1] + wsum[2] + wsum[3];
        atomicAdd(loss_acc + (blockIdx.x & (NSLOT - 1)), (double)s);
    }
}

// ---------------------------------------------------------------------------
// Kernel D: loss = (1 + beta) * sum / NOUT
// ---------------------------------------------------------------------------
__global__ void finalize_kernel(const double* __restrict__ loss_acc,
                                float* __restrict__ out_loss) {
    if (threadIdx.x == 0) {
        double s = 0.0;
        for (int i = 0; i < NSLOT; ++i) s += loss_acc[i];
        *out_loss = (float)(1.25 * s / (double)NOUT);
    }
}

extern "C" void kernel_launch(void* const* d_in, const int* in_sizes, int n_in,
                              void* d_out, int out_size, void* d_ws, size_t ws_size,
                              hipStream_t stream) {
    const float* z = (const float*)d_in[0];
    const float* cb = (const float*)d_in[1];

    float* out = (float*)d_out;            // [16,256,64,64]
    float* loss_out = out + NOUT;          // scalar
    float* idx_out = out + NOUT + 1;       // [16,1,64,64] as float

    // workspace layout (total ~1.32 MB):
    //   [0, 2048)                 : double loss_acc[NSLOT]
    //   [2048, 6144)              : float  cnorm[1024]
    //   [6144, 268288)            : int    idx_ws[65536]
    //   [268288, 1316864)         : float  cbT[256][1024]
    double* loss_acc = (double*)d_ws;
    float* cnorm = (float*)((char*)d_ws + 2048);
    int* idx_ws = (int*)((char*)d_ws + 2048 + 4096);
    float* cbT = (float*)((char*)d_ws + 2048 + 4096 + NPOS * 4);

    hipMemsetAsync(d_ws, 0, 2048, stream);
    cnorm_kernel<<<(NK + 255) / 256, 256, 0, stream>>>(cb, cnorm);
    transpose_cb_kernel<<<NK, 256, 0, stream>>>(cb, cbT);
    argmin_kernel<<<NPOS / 64, 512, 0, stream>>>(z, cbT, cnorm, idx_ws, idx_out);
    gather_loss_kernel<<<NOUT / 1024, 256, 0, stream>>>(z, cb, idx_ws, out, loss_acc);
    finalize_kernel<<<1, 64, 0, stream>>>(loss_acc, loss_out);
}

// Round 3
// 621.882 us; speedup vs baseline: 1.2173x; 1.2173x over previous
//
#include <hip/hip_runtime.h>

#define NB 16
#define NC 256
#define NH 64
#define NW 64
#define NK 1024
#define HW (NH * NW)          // 4096
#define NPOS (NB * HW)        // 65536
#define NOUT (NB * NC * HW)   // 16777216
#define NSLOT 256             // loss accumulator slots (atomic spreading)

__device__ __forceinline__ float sq_rn(float x) { return __fmul_rn(x, x); }

// Exact replica of numpy pairwise_sum for sum(a*a) over n=256 (verified R2/R4).
__device__ __forceinline__ float pairwise_sumsq_256(const float* __restrict__ a,
                                                    int stride) {
    float s_half[2];
#pragma unroll
    for (int h = 0; h < 2; ++h) {
        const float* base = a + (size_t)(h * 128) * stride;
        float r[8];
#pragma unroll
        for (int j = 0; j < 8; ++j) r[j] = sq_rn(base[(size_t)j * stride]);
        for (int i = 8; i < 128; i += 8) {
#pragma unroll
            for (int j = 0; j < 8; ++j)
                r[j] = __fadd_rn(r[j], sq_rn(base[(size_t)(i + j) * stride]));
        }
        s_half[h] = __fadd_rn(
            __fadd_rn(__fadd_rn(r[0], r[1]), __fadd_rn(r[2], r[3])),
            __fadd_rn(__fadd_rn(r[4], r[5]), __fadd_rn(r[6], r[7])));
    }
    return __fadd_rn(s_half[0], s_half[1]);
}

// ---------------------------------------------------------------------------
// Kernel A: cnorm[k] = numpy-fp32 sum(codebook[k]^2)
// ---------------------------------------------------------------------------
__global__ __launch_bounds__(256) void cnorm_kernel(const float* __restrict__ cb,
                                                    float* __restrict__ cnorm) {
    int k = blockIdx.x * 256 + threadIdx.x;
    if (k < NK) {
        cnorm[k] = pairwise_sumsq_256(cb + (size_t)k * NC, 1);
    }
}

// ---------------------------------------------------------------------------
// Kernel A2: cbT[d][k] = cb[k][d]  (d-major codebook for streamed argmin loads)
// ---------------------------------------------------------------------------
__global__ __launch_bounds__(256) void transpose_cb_kernel(const float* __restrict__ cb,
                                                           float* __restrict__ cbT) {
    const int k = blockIdx.x;    // 0..1023
    const int d = threadIdx.x;   // 0..255
    cbT[(size_t)d * NK + k] = cb[(size_t)k * NC + d];
}

// ---------------------------------------------------------------------------
// Kernel B (R9 = R8 with the register cap fixed):
// R8 post-mortem: __launch_bounds__(512,4) forced VGPR=64 -> acc[8][8]
// spilled to scratch (WRITE_SIZE 544KB -> 108MB, argmin 473 -> 673 us).
// R9: __launch_bounds__(512,2) -> VGPR cap >=128; R7 proved this body fits
// in 116 VGPR, so no spill. LDS 70KB -> 2 blocks/CU; 8-wave blocks ->
// 16 waves/CU = 4 waves/SIMD (2x R7's latency hiding) WITHOUT scratch.
// Bit-exact vs R6/R7/R8: acc = same sequential __fmaf_rn chain over
// ascending d; score = fl(fl(znorm+cnorm) - 2*dot); per-thread k strictly
// ascending across passes; tie-breaks kept in both reduces.
// ---------------------------------------------------------------------------
__global__ __launch_bounds__(512, 2) void argmin_kernel(const float* __restrict__ z,
                                                        const float* __restrict__ cbT,
                                                        const float* __restrict__ cnorm,
                                                        int* __restrict__ idx_ws,
                                                        float* __restrict__ idx_out) {
    __shared__ float z_lds[256][64];      // 65536 B, [d][p]
    __shared__ float znorm_s[64];         //   256 B
    __shared__ float red_v[8][64];        //  2048 B
    __shared__ int   red_i[8][64];        //  2048 B   -> ~68.25 KB, 2 blk/CU

    const int blk = blockIdx.x;           // 0..1023
    const int b = blk >> 6;               // batch
    const int hw0 = (blk & 63) * 64;      // h-row base (64 contiguous positions)
    const int t = threadIdx.x;            // 0..511
    const int lane = t & 63;
    const int wave = t >> 6;              // 0..7
    const int pg = lane & 7;              // position group (8 pos each)
    const int cg = lane >> 3;             // code group (8 codes each)

    const float* zg = z + (size_t)b * (NC * HW) + hw0;

    // ---- stage z d-major: 8 iters of float4 across 512 threads (coalesced)
#pragma unroll
    for (int i = 0; i < 8; ++i) {
        const int flat4 = i * 2048 + t * 4;   // multiple of 4
        const int d = flat4 >> 6;
        const int p = flat4 & 63;
        const float4 v = *(const float4*)(zg + (size_t)d * HW + p);
        *(float4*)&z_lds[d][p] = v;
    }
    // numpy-exact znorm (same global-strided code path verified in R2/R4)
    if (wave == 0) znorm_s[lane] = pairwise_sumsq_256(zg + lane, HW);
    __syncthreads();                      // the ONLY pre-reduce barrier

    float best[8];
    int bid[8];
#pragma unroll
    for (int i = 0; i < 8; ++i) { best[i] = 3.4e38f; bid[i] = 0; }

#pragma unroll 1
    for (int pass = 0; pass < 2; ++pass) {
        float acc[8][8];
#pragma unroll
        for (int i = 0; i < 8; ++i)
#pragma unroll
            for (int j = 0; j < 8; ++j) acc[i][j] = 0.f;

        // wave owns codes [wave*128, wave*128+128); this pass's 64 of them.
        const int k0 = wave * 128 + pass * 64 + cg * 8;
        const float* cp = cbT + k0;       // column base; row stride NK floats

#pragma unroll 1
        for (int it = 0; it < 64; ++it) { // 4 dims per chunk, register-lean
            const int ds = it * 4;
            float4 cbuf[8];               // 32 VGPR in flight
#pragma unroll
            for (int q = 0; q < 8; ++q)
                cbuf[q] = *(const float4*)(cp + (size_t)(ds + (q >> 1)) * NK
                                              + (q & 1) * 4);
#pragma unroll
            for (int dl = 0; dl < 4; ++dl) {
                const int d = ds + dl;
                const float4 za = *(const float4*)&z_lds[d][pg * 8];
                const float4 zb = *(const float4*)&z_lds[d][pg * 8 + 4];
                const float zf[8] = {za.x, za.y, za.z, za.w,
                                     zb.x, zb.y, zb.z, zb.w};
                const float4 ca = cbuf[dl * 2];
                const float4 cc = cbuf[dl * 2 + 1];
                const float cf[8] = {ca.x, ca.y, ca.z, ca.w,
                                     cc.x, cc.y, cc.z, cc.w};
#pragma unroll
                for (int i = 0; i < 8; ++i)
#pragma unroll
                    for (int j = 0; j < 8; ++j)
                        acc[i][j] = __fmaf_rn(zf[i], cf[j], acc[i][j]);
            }
        }

        // scores for this pass's 8 codes of this thread (k ascending within
        // thread across passes -> strict < keeps first occurrence)
        const float4 cn0 = *(const float4*)(cnorm + k0);
        const float4 cn1 = *(const float4*)(cnorm + k0 + 4);
        const float cnf[8] = {cn0.x, cn0.y, cn0.z, cn0.w,
                              cn1.x, cn1.y, cn1.z, cn1.w};
        float znl[8];
#pragma unroll
        for (int i = 0; i < 8; ++i) znl[i] = znorm_s[pg * 8 + i];
#pragma unroll
        for (int j = 0; j < 8; ++j) {
            const int k = k0 + j;
#pragma unroll
            for (int i = 0; i < 8; ++i) {
                const float sc = __fsub_rn(__fadd_rn(znl[i], cnf[j]),
                                           __fmul_rn(2.0f, acc[i][j]));
                if (sc < best[i]) { best[i] = sc; bid[i] = k; }
            }
        }
    }

    // ---- reduce across cg (lane stride 8). k-ranges of different cg lanes
    //      INTERLEAVE across passes -> must tie-break on lower index to match
    //      np.argmin first-occurrence (R5 bug).
#pragma unroll
    for (int off = 32; off >= 8; off >>= 1) {
#pragma unroll
        for (int i = 0; i < 8; ++i) {
            const float v = __shfl_down(best[i], off, 64);
            const int d2 = __shfl_down(bid[i], off, 64);
            if (v < best[i] || (v == best[i] && d2 < bid[i])) {
                best[i] = v;
                bid[i] = d2;
            }
        }
    }
    if (cg == 0) {
#pragma unroll
        for (int i = 0; i < 8; ++i) {
            red_v[wave][pg * 8 + i] = best[i];
            red_i[wave][pg * 8 + i] = bid[i];
        }
    }
    __syncthreads();

    // ---- final reduce across 8 waves (disjoint ascending k ranges; index
    //      tie-break kept anyway for safety)
    if (t < 64) {
        float bv = red_v[0][t];
        int bi = red_i[0][t];
#pragma unroll
        for (int w = 1; w < 8; ++w) {
            const float v = red_v[w][t];
            const int i2 = red_i[w][t];
            if (v < bv || (v == bv && i2 < bi)) { bv = v; bi = i2; }
        }
        const int g = b * HW + hw0 + t;
        idx_ws[g] = bi;
        idx_out[g] = (float)bi;
    }
}

// ---------------------------------------------------------------------------
// Kernel C: out[b,c,h,w] = cb[idx[b,h,w]][c]; accumulate sum((zq - z)^2)
// Atomics spread over NSLOT slots (R7 win).
// ---------------------------------------------------------------------------
__global__ __launch_bounds__(256) void gather_loss_kernel(const float* __restrict__ z,
                                                          const float* __restrict__ cb,
                                                          const int* __restrict__ idx_ws,
                                                          float* __restrict__ out,
                                                          double* __restrict__ loss_acc) {
    const unsigned g = blockIdx.x * 256u + threadIdx.x;  // float4 index
    const unsigned e = g * 4u;                           // element index
    const unsigned w = e & 63u;
    const unsigned h = (e >> 6) & 63u;
    const unsigned c = (e >> 12) & 255u;
    const unsigned b = e >> 20;

    const unsigned p = b * HW + h * NW + w;  // divisible by 4

    const int4 iv = *(const int4*)(idx_ws + p);
    const float4 z4 = *(const float4*)(z + e);

    float4 o;
    o.x = cb[(size_t)iv.x * NC + c];
    o.y = cb[(size_t)iv.y * NC + c];
    o.z = cb[(size_t)iv.z * NC + c];
    o.w = cb[(size_t)iv.w * NC + c];

    *(float4*)(out + e) = o;

    const float d0 = o.x - z4.x;
    const float d1 = o.y - z4.y;
    const float d2 = o.z - z4.z;
    const float d3 = o.w - z4.w;
    float part = d0 * d0 + d1 * d1 + d2 * d2 + d3 * d3;

#pragma unroll
    for (int off = 32; off > 0; off >>= 1) part += __shfl_down(part, off, 64);

    __shared__ float wsum[4];
    const int lane = threadIdx.x & 63;
    const int wave = threadIdx.x >> 6;
    if (lane == 0) wsum[wave] = part;
    __syncthreads();
    if (threadIdx.x == 0) {
        float s = wsum[0] + wsum[1] + wsum[2] + wsum[3];
        atomicAdd(loss_acc + (blockIdx.x & (NSLOT - 1)), (double)s);
    }
}

// ---------------------------------------------------------------------------
// Kernel D: loss = (1 + beta) * sum / NOUT
// ---------------------------------------------------------------------------
__global__ void finalize_kernel(const double* __restrict__ loss_acc,
                                float* __restrict__ out_loss) {
    if (threadIdx.x == 0) {
        double s = 0.0;
        for (int i = 0; i < NSLOT; ++i) s += loss_acc[i];
        *out_loss = (float)(1.25 * s / (double)NOUT);
    }
}

extern "C" void kernel_launch(void* const* d_in, const int* in_sizes, int n_in,
                              void* d_out, int out_size, void* d_ws, size_t ws_size,
                              hipStream_t stream) {
    const float* z = (const float*)d_in[0];
    const float* cb = (const float*)d_in[1];

    float* out = (float*)d_out;            // [16,256,64,64]
    float* loss_out = out + NOUT;          // scalar
    float* idx_out = out + NOUT + 1;       // [16,1,64,64] as float

    // workspace layout (total ~1.32 MB):
    //   [0, 2048)                 : double loss_acc[NSLOT]
    //   [2048, 6144)              : float  cnorm[1024]
    //   [6144, 268288)            : int    idx_ws[65536]
    //   [268288, 1316864)         : float  cbT[256][1024]
    double* loss_acc = (double*)d_ws;
    float* cnorm = (float*)((char*)d_ws + 2048);
    int* idx_ws = (int*)((char*)d_ws + 2048 + 4096);
    float* cbT = (float*)((char*)d_ws + 2048 + 4096 + NPOS * 4);

    hipMemsetAsync(d_ws, 0, 2048, stream);
    cnorm_kernel<<<(NK + 255) / 256, 256, 0, stream>>>(cb, cnorm);
    transpose_cb_kernel<<<NK, 256, 0, stream>>>(cb, cbT);
    argmin_kernel<<<NPOS / 64, 512, 0, stream>>>(z, cbT, cnorm, idx_ws, idx_out);
    gather_loss_kernel<<<NOUT / 1024, 256, 0, stream>>>(z, cb, idx_ws, out, loss_acc);
    finalize_kernel<<<1, 64, 0, stream>>>(loss_acc, loss_out);
}

// Round 4
// 580.285 us; speedup vs baseline: 1.3046x; 1.0717x over previous
//
#include <hip/hip_runtime.h>

#define NB 16
#define NC 256
#define NH 64
#define NW 64
#define NK 1024
#define HW (NH * NW)          // 4096
#define NPOS (NB * HW)        // 65536
#define NOUT (NB * NC * HW)   // 16777216
#define NSLOT 256             // loss accumulator slots (atomic spreading)

__device__ __forceinline__ float sq_rn(float x) { return __fmul_rn(x, x); }

// Exact replica of numpy pairwise_sum for sum(a*a) over n=256 (verified R2/R4).
__device__ __forceinline__ float pairwise_sumsq_256(const float* __restrict__ a,
                                                    int stride) {
    float s_half[2];
#pragma unroll
    for (int h = 0; h < 2; ++h) {
        const float* base = a + (size_t)(h * 128) * stride;
        float r[8];
#pragma unroll
        for (int j = 0; j < 8; ++j) r[j] = sq_rn(base[(size_t)j * stride]);
        for (int i = 8; i < 128; i += 8) {
#pragma unroll
            for (int j = 0; j < 8; ++j)
                r[j] = __fadd_rn(r[j], sq_rn(base[(size_t)(i + j) * stride]));
        }
        s_half[h] = __fadd_rn(
            __fadd_rn(__fadd_rn(r[0], r[1]), __fadd_rn(r[2], r[3])),
            __fadd_rn(__fadd_rn(r[4], r[5]), __fadd_rn(r[6], r[7])));
    }
    return __fadd_rn(s_half[0], s_half[1]);
}

// ---------------------------------------------------------------------------
// Kernel A: cnorm[k] = numpy-fp32 sum(codebook[k]^2)
// ---------------------------------------------------------------------------
__global__ __launch_bounds__(256) void cnorm_kernel(const float* __restrict__ cb,
                                                    float* __restrict__ cnorm) {
    int k = blockIdx.x * 256 + threadIdx.x;
    if (k < NK) {
        cnorm[k] = pairwise_sumsq_256(cb + (size_t)k * NC, 1);
    }
}

// ---------------------------------------------------------------------------
// Kernel A2 (R10): pack codebook as cbT2[d/4][k][4]:
//   cbT2[((d>>2)*NK + k)*4 + (d&3)] = cb[k][d]
// A thread's 8 codes x 4 dims = 128 CONTIGUOUS bytes -> 8 dwordx4 loads from
// one base pointer with offset immediates (kills the per-row 64-bit address
// arithmetic that was ~18% of VALU cycles in R9).
// ---------------------------------------------------------------------------
__global__ __launch_bounds__(256) void pack_cb_kernel(const float* __restrict__ cb,
                                                      float* __restrict__ cbT2) {
    const int k = blockIdx.x;    // 0..1023
    const int d = threadIdx.x;   // 0..255
    cbT2[(size_t)((d >> 2) * NK + k) * 4 + (d & 3)] = cb[(size_t)k * NC + d];
}

// ---------------------------------------------------------------------------
// Kernel B (R10): R9 core + packed-cb addressing + fused gather/loss.
// R9 post-mortem: 44.5% of cycles FMA issue, ~17.5% non-FMA VALU (address
// arithmetic: cbT rows 4KB apart exceed the 13-bit load immediate -> LLVM
// kept 4-8 64-bit pointers; runtime LDS offsets), ~38% idle; TLP doubling
// (R7->R9) changed nothing -> VALU-work-bound, not latency-bound. Effective
// VALU throughput was ~95% of the m07-measured 103 TF chip FMA ceiling.
// R10: (a) cbT2 packed layout -> 1 pointer increment + immediate offsets per
// iteration; (b) gather+loss fused here (z_lds already holds z[c][p]; final
// idx published via LDS) -> saves 64MB z HBM re-read + idx round-trip +
// a launch.
// Bit-exact: acc = same sequential __fmaf_rn chain over ascending d (only
// the cb load PATH changed, not the order); score = fl(fl(zn+cn)-2*dot);
// per-thread k ascending across passes; tie-breaks in both reduces.
// ---------------------------------------------------------------------------
__global__ __launch_bounds__(512, 2) void argmin_kernel(const float* __restrict__ z,
                                                        const float* __restrict__ cb,
                                                        const float* __restrict__ cbT2,
                                                        const float* __restrict__ cnorm,
                                                        float* __restrict__ out,
                                                        float* __restrict__ idx_out,
                                                        double* __restrict__ loss_acc) {
    __shared__ float z_lds[256][64];      // 65536 B, [d][p] == [c][p]
    __shared__ float znorm_s[64];         //   256 B
    __shared__ float red_v[8][64];        //  2048 B
    __shared__ int   red_i[8][64];        //  2048 B   -> ~68.25 KB, 2 blk/CU

    const int blk = blockIdx.x;           // 0..1023
    const int b = blk >> 6;               // batch
    const int hw0 = (blk & 63) * 64;      // h-row base (64 contiguous positions)
    const int t = threadIdx.x;            // 0..511
    const int lane = t & 63;
    const int wave = t >> 6;              // 0..7
    const int pg = lane & 7;              // position group (8 pos each)
    const int cg = lane >> 3;             // code group (8 codes each)

    const float* zg = z + (size_t)b * (NC * HW) + hw0;

    // ---- stage z d-major: 8 iters of float4 across 512 threads (coalesced)
#pragma unroll
    for (int i = 0; i < 8; ++i) {
        const int flat4 = i * 2048 + t * 4;   // multiple of 4
        const int d = flat4 >> 6;
        const int p = flat4 & 63;
        const float4 v = *(const float4*)(zg + (size_t)d * HW + p);
        *(float4*)&z_lds[d][p] = v;
    }
    // numpy-exact znorm (same global-strided code path verified in R2/R4)
    if (wave == 0) znorm_s[lane] = pairwise_sumsq_256(zg + lane, HW);
    __syncthreads();                      // the ONLY pre-reduce barrier

    float best[8];
    int bid[8];
#pragma unroll
    for (int i = 0; i < 8; ++i) { best[i] = 3.4e38f; bid[i] = 0; }

#pragma unroll 1
    for (int pass = 0; pass < 2; ++pass) {
        float acc[8][8];
#pragma unroll
        for (int i = 0; i < 8; ++i)
#pragma unroll
            for (int j = 0; j < 8; ++j) acc[i][j] = 0.f;

        // wave owns codes [wave*128, wave*128+128); this pass's 64 of them.
        const int k0 = wave * 128 + pass * 64 + cg * 8;
        const float* cp2 = cbT2 + (size_t)k0 * 4;   // this thread's code base

#pragma unroll 1
        for (int it = 0; it < 64; ++it) { // 4 dims per chunk
            // 8 codes x 4 dims = 128 contiguous bytes: one base + immediates
            float4 cbuf[8];
#pragma unroll
            for (int q = 0; q < 8; ++q)
                cbuf[q] = *(const float4*)(cp2 + (size_t)it * 4096 + q * 4);
#pragma unroll
            for (int dl = 0; dl < 4; ++dl) {
                const int d = it * 4 + dl;
                const float4 za = *(const float4*)&z_lds[d][pg * 8];
                const float4 zb = *(const float4*)&z_lds[d][pg * 8 + 4];
                const float zf[8] = {za.x, za.y, za.z, za.w,
                                     zb.x, zb.y, zb.z, zb.w};
#pragma unroll
                for (int i = 0; i < 8; ++i)
#pragma unroll
                    for (int j = 0; j < 8; ++j)
                        acc[i][j] = __fmaf_rn(zf[i],
                                              ((const float*)&cbuf[j])[dl],
                                              acc[i][j]);
            }
        }

        // scores for this pass's 8 codes of this thread (k ascending within
        // thread across passes -> strict < keeps first occurrence)
        const float4 cn0 = *(const float4*)(cnorm + k0);
        const float4 cn1 = *(const float4*)(cnorm + k0 + 4);
        const float cnf[8] = {cn0.x, cn0.y, cn0.z, cn0.w,
                              cn1.x, cn1.y, cn1.z, cn1.w};
        float znl[8];
#pragma unroll
        for (int i = 0; i < 8; ++i) znl[i] = znorm_s[pg * 8 + i];
#pragma unroll
        for (int j = 0; j < 8; ++j) {
            const int k = k0 + j;
#pragma unroll
            for (int i = 0; i < 8; ++i) {
                const float sc = __fsub_rn(__fadd_rn(znl[i], cnf[j]),
                                           __fmul_rn(2.0f, acc[i][j]));
                if (sc < best[i]) { best[i] = sc; bid[i] = k; }
            }
        }
    }

    // ---- reduce across cg (lane stride 8). k-ranges of different cg lanes
    //      INTERLEAVE across passes -> must tie-break on lower index to match
    //      np.argmin first-occurrence (R5 bug).
#pragma unroll
    for (int off = 32; off >= 8; off >>= 1) {
#pragma unroll
        for (int i = 0; i < 8; ++i) {
            const float v = __shfl_down(best[i], off, 64);
            const int d2 = __shfl_down(bid[i], off, 64);
            if (v < best[i] || (v == best[i] && d2 < bid[i])) {
                best[i] = v;
                bid[i] = d2;
            }
        }
    }
    if (cg == 0) {
#pragma unroll
        for (int i = 0; i < 8; ++i) {
            red_v[wave][pg * 8 + i] = best[i];
            red_i[wave][pg * 8 + i] = bid[i];
        }
    }
    __syncthreads();

    // ---- final reduce across 8 waves; publish final idx in red_i[0][p]
    if (t < 64) {
        float bv = red_v[0][t];
        int bi = red_i[0][t];
#pragma unroll
        for (int w = 1; w < 8; ++w) {
            const float v = red_v[w][t];
            const int i2 = red_i[w][t];
            if (v < bv || (v == bv && i2 < bi)) { bv = v; bi = i2; }
        }
        idx_out[b * HW + hw0 + t] = (float)bi;
        red_i[0][t] = bi;                 // each t touches only column t: safe
    }
    __syncthreads();

    // ---- fused gather + loss: out[b][c][hw0+p] = cb[idx[p]][c];
    //      z_lds[c][p] still holds z for this tile (same bits as global z).
    float* outg = out + (size_t)b * (NC * HW) + hw0;
    float lsum = 0.f;
#pragma unroll 1
    for (int r = 0; r < 8; ++r) {
        const int id = r * 512 + t;       // 0..4095 = [c 0..255][p4 0..15]
        const int c = id >> 4;
        const int p4 = (id & 15) * 4;
        const int i0 = red_i[0][p4];
        const int i1 = red_i[0][p4 + 1];
        const int i2 = red_i[0][p4 + 2];
        const int i3 = red_i[0][p4 + 3];
        float4 o;
        o.x = cb[(size_t)i0 * NC + c];
        o.y = cb[(size_t)i1 * NC + c];
        o.z = cb[(size_t)i2 * NC + c];
        o.w = cb[(size_t)i3 * NC + c];
        *(float4*)(outg + (size_t)c * HW + p4) = o;
        const float4 zv = *(const float4*)&z_lds[c][p4];
        const float d0 = o.x - zv.x;
        const float d1 = o.y - zv.y;
        const float d2 = o.z - zv.z;
        const float d3 = o.w - zv.w;
        lsum += d0 * d0 + d1 * d1 + d2 * d2 + d3 * d3;
    }
#pragma unroll
    for (int off = 32; off > 0; off >>= 1) lsum += __shfl_down(lsum, off, 64);
    if (lane == 0) red_v[wave][0] = lsum;
    __syncthreads();
    if (t == 0) {
        float s = 0.f;
#pragma unroll
        for (int w = 0; w < 8; ++w) s += red_v[w][0];
        atomicAdd(loss_acc + (blk & (NSLOT - 1)), (double)s);
    }
}

// ---------------------------------------------------------------------------
// Kernel D: loss = (1 + beta) * sum / NOUT
// ---------------------------------------------------------------------------
__global__ void finalize_kernel(const double* __restrict__ loss_acc,
                                float* __restrict__ out_loss) {
    if (threadIdx.x == 0) {
        double s = 0.0;
        for (int i = 0; i < NSLOT; ++i) s += loss_acc[i];
        *out_loss = (float)(1.25 * s / (double)NOUT);
    }
}

extern "C" void kernel_launch(void* const* d_in, const int* in_sizes, int n_in,
                              void* d_out, int out_size, void* d_ws, size_t ws_size,
                              hipStream_t stream) {
    const float* z = (const float*)d_in[0];
    const float* cb = (const float*)d_in[1];

    float* out = (float*)d_out;            // [16,256,64,64]
    float* loss_out = out + NOUT;          // scalar
    float* idx_out = out + NOUT + 1;       // [16,1,64,64] as float

    // workspace layout (~1.06 MB):
    //   [0, 2048)        : double loss_acc[NSLOT]
    //   [2048, 6144)     : float  cnorm[1024]
    //   [6144, 1054720)  : float  cbT2[64][1024][4]
    double* loss_acc = (double*)d_ws;
    float* cnorm = (float*)((char*)d_ws + 2048);
    float* cbT2 = (float*)((char*)d_ws + 2048 + 4096);

    hipMemsetAsync(d_ws, 0, 2048, stream);
    cnorm_kernel<<<(NK + 255) / 256, 256, 0, stream>>>(cb, cnorm);
    pack_cb_kernel<<<NK, 256, 0, stream>>>(cb, cbT2);
    argmin_kernel<<<NPOS / 64, 512, 0, stream>>>(z, cb, cbT2, cnorm,
                                                 out, idx_out, loss_acc);
    finalize_kernel<<<1, 64, 0, stream>>>(loss_acc, loss_out);
}